// Round 4
// baseline (585.531 us; speedup 1.0000x reference)
//
#include <hip/hip_runtime.h>
#include <math.h>

#define N_NODES 50000
#define N_EDGES 400000
#define F_DIM   128
#define N_RBF   20
#define SCAN_B  256
#define N_CHUNK ((N_NODES + SCAN_B - 1) / SCAN_B)   // 196

typedef float f2 __attribute__((ext_vector_type(2)));

// ---------------------------------------------------------------------------
// phi_table[t] = silu(emb_table[t] @ w_phi1 + b_phi1) @ w_phi2 + b_phi2
// ---------------------------------------------------------------------------
__global__ void phi_table_kernel(const float* __restrict__ emb_table,
                                 const float* __restrict__ w_phi1,
                                 const float* __restrict__ b_phi1,
                                 const float* __restrict__ w_phi2,
                                 const float* __restrict__ b_phi2,
                                 float* __restrict__ phi_table) {
    __shared__ float emb_s[F_DIM];
    __shared__ float h_s[F_DIM];
    const int t = blockIdx.x;
    const int o = threadIdx.x;
    if (o < F_DIM) emb_s[o] = emb_table[t * F_DIM + o];
    __syncthreads();
    if (o < F_DIM) {
        float acc = b_phi1[o];
#pragma unroll 8
        for (int k = 0; k < F_DIM; ++k)
            acc = fmaf(emb_s[k], w_phi1[k * F_DIM + o], acc);
        h_s[o] = acc / (1.0f + expf(-acc));   // silu
    }
    __syncthreads();
    float a2 = b_phi2[o];
#pragma unroll 8
    for (int k = 0; k < F_DIM; ++k)
        a2 = fmaf(h_s[k], w_phi2[k * (3 * F_DIM) + o], a2);
    phi_table[t * (3 * F_DIM) + o] = a2;
}

__global__ void count_kernel(const int* __restrict__ edst, int* __restrict__ counts) {
    const int e = blockIdx.x * blockDim.x + threadIdx.x;
    if (e < N_EDGES) atomicAdd(&counts[edst[e]], 1);
}

__global__ void scan_partial_kernel(const int* __restrict__ counts,
                                    int* __restrict__ partial,
                                    int* __restrict__ chunk_sums) {
    __shared__ int s[SCAN_B];
    const int tid = threadIdx.x;
    const int gid = blockIdx.x * SCAN_B + tid;
    const int v = (gid < N_NODES) ? counts[gid] : 0;
    s[tid] = v;
    __syncthreads();
    for (int d = 1; d < SCAN_B; d <<= 1) {
        const int t = (tid >= d) ? s[tid - d] : 0;
        __syncthreads();
        s[tid] += t;
        __syncthreads();
    }
    if (gid < N_NODES) partial[gid] = s[tid] - v;
    if (tid == SCAN_B - 1) chunk_sums[blockIdx.x] = s[tid];
}

__global__ void scan_sums_kernel(int* __restrict__ chunk_sums,
                                 int* __restrict__ chunk_pref) {
    __shared__ int s[SCAN_B];
    const int tid = threadIdx.x;
    const int v = (tid < N_CHUNK) ? chunk_sums[tid] : 0;
    s[tid] = v;
    __syncthreads();
    for (int d = 1; d < SCAN_B; d <<= 1) {
        const int t = (tid >= d) ? s[tid - d] : 0;
        __syncthreads();
        s[tid] += t;
        __syncthreads();
    }
    if (tid < N_CHUNK) chunk_pref[tid] = s[tid] - v;
}

__global__ void finalize_offsets_kernel(const int* __restrict__ partial,
                                        const int* __restrict__ chunk_pref,
                                        int* __restrict__ offsets,
                                        int* __restrict__ cursor) {
    const int i = blockIdx.x * blockDim.x + threadIdx.x;
    if (i >= N_NODES) return;
    const int o = partial[i] + chunk_pref[i >> 8];
    offsets[i] = o;
    cursor[i]  = o;
}

// ---------------------------------------------------------------------------
// Edge-parallel precompute + CSR fill. Per edge, one 32B record at slot p:
//   rec[2p]   = (px, py, pz, d)
//   rec[2p+1] = (j, t, sin(a)/d, 2*cos(a))   [a = pi*d/5]
// ---------------------------------------------------------------------------
__global__ void edge_pre_kernel(const float* __restrict__ pos,
                                const int* __restrict__ z,
                                const int* __restrict__ esrc,
                                const int* __restrict__ edst,
                                int* __restrict__ cursor,
                                float4* __restrict__ rec) {
    const int e = blockIdx.x * blockDim.x + threadIdx.x;
    if (e >= N_EDGES) return;
    const int j = esrc[e];
    const int i = edst[e];
    const int p = atomicAdd(&cursor[i], 1);

    const float px = pos[3 * i + 0] - pos[3 * j + 0];
    const float py = pos[3 * i + 1] - pos[3 * j + 1];
    const float pz = pos[3 * i + 2] - pos[3 * j + 2];
    const float d = sqrtf(px * px + py * py + pz * pz);
    const float inv_d = 1.0f / d;

    float sa, ca;
    sincosf(0.6283185307179586f * d, &sa, &ca);   // pi*d/5

    rec[2 * p] = make_float4(px, py, pz, d);
    float4 b;
    b.x = __int_as_float(j);
    b.y = __int_as_float(z[j]);
    b.z = sa * inv_d;
    b.w = 2.0f * ca;
    rec[2 * p + 1] = b;
}

// ---------------------------------------------------------------------------
// Gather: 128-thread group per node (2/block). Thread f owns outputs
// f, 128+f, 256+f.
//
// R3 post-mortem: VALU ISSUE VOLUME is the binding resource (181 µs issued
// vs ~59 µs essential). R4: process edges in PAIRS with the entire
// W/Chebyshev hot block as float2 -> v_pk_fma_f32 (VOP3P packed fp32,
// 2 FMA per issue slot; this is how MI355X reaches 157 TF fp32).
// One edge per vector half; weights are splat operands (free via
// op_sel_hi). Identical per-element fp32 math -> bit-identical results.
// Pair granularity also halves weight reloads (30/edge) and keeps tail
// waste at ~6% (vs 19% at EC=4). Epilogue stays scalar (packing it costs
// as many shuffle movs as it saves).
// ---------------------------------------------------------------------------
__global__ void __launch_bounds__(256, 2)
gather_kernel(const float* __restrict__ eq,
              const float* __restrict__ emb_table,
              const float* __restrict__ phi_table,
              const float* __restrict__ w_rbf,
              const float* __restrict__ b_rbf,
              const int* __restrict__ z,
              const float4* __restrict__ rec,
              const int* __restrict__ offsets,
              const int* __restrict__ counts,
              float* __restrict__ out_emb,
              float* __restrict__ out_eq) {
    const int tid = threadIdx.x;
    const int grp = tid >> 7;
    const int f   = tid & 127;
    const int i   = blockIdx.x * 2 + grp;
    if (i >= N_NODES) return;

    const int start = offsets[i];
    const int cnt   = counts[i];

    const float br1 = b_rbf[f];
    const float br2 = b_rbf[F_DIM + f];
    const float br3 = b_rbf[2 * F_DIM + f];
    const float* wbase = w_rbf + f;

    float accE = 0.f, ax = 0.f, ay = 0.f, az = 0.f;

    if (cnt > 0) {
        const int last = cnt - 1;

        // prologue: current pair's records
        float4 A0 = rec[2 * start];
        float4 B0 = rec[2 * start + 1];
        const int p1 = start + min(1, last);
        float4 A1 = rec[2 * p1];
        float4 B1 = rec[2 * p1 + 1];

        for (int base = 0; base < cnt; base += 2) {
            // prefetch next pair's records (clamped; dup on tail is harmless)
            const int pn0 = start + min(base + 2, last);
            const int pn1 = start + min(base + 3, last);
            const float4 A2 = rec[2 * pn0];
            const float4 B2 = rec[2 * pn0 + 1];
            const float4 A3 = rec[2 * pn1];
            const float4 B3 = rec[2 * pn1 + 1];

            // issue eq/phi gathers for the current pair (latency hidden
            // under the 80-slot packed FMA block below)
            const int ja = __float_as_int(B0.x), ta = __float_as_int(B0.y);
            const int jb = __float_as_int(B1.x), tb = __float_as_int(B1.y);
            const float* eja = eq + ((size_t)ja * F_DIM + f) * 3;
            const float* ejb = eq + ((size_t)jb * F_DIM + f) * 3;
            const float eqa0 = eja[0], eqa1 = eja[1], eqa2 = eja[2];
            const float eqb0 = ejb[0], eqb1 = ejb[1], eqb2 = ejb[2];
            const float* pta = phi_table + ta * (3 * F_DIM) + f;
            const float* ptb = phi_table + tb * (3 * F_DIM) + f;
            const float pha0 = pta[0], pha1 = pta[F_DIM], pha2 = pta[2 * F_DIM];
            // slot b masked on tail (kills its contribution exactly)
            const float mb = (base + 1 < cnt) ? 1.0f : 0.0f;
            const float phb0 = mb * ptb[0];
            const float phb1 = mb * ptb[F_DIM];
            const float phb2 = mb * ptb[2 * F_DIM];

            // ---- packed hot block: 2 edges per v_pk_fma_f32 ----
            f2 W1 = {br1, br1};
            f2 W2 = {br2, br2};
            f2 W3 = {br3, br3};
            f2 tc   = {B0.z, B1.z};
            f2 twoc = {B0.w, B1.w};
            f2 tm1  = {0.0f, 0.0f};
#pragma unroll
            for (int n = 0; n < N_RBF; ++n) {
                const float w1 = wbase[n * (3 * F_DIM)];
                const float w2 = wbase[n * (3 * F_DIM) + F_DIM];
                const float w3 = wbase[n * (3 * F_DIM) + 2 * F_DIM];
                const f2 w1v = {w1, w1};
                const f2 w2v = {w2, w2};
                const f2 w3v = {w3, w3};
                W1 = __builtin_elementwise_fma(tc, w1v, W1);
                W2 = __builtin_elementwise_fma(tc, w2v, W2);
                W3 = __builtin_elementwise_fma(tc, w3v, W3);
                const f2 tn = __builtin_elementwise_fma(twoc, tc, -tm1);
                tm1 = tc; tc = tn;
            }

            // ---- scalar epilogue, slot a ----
            accE = fmaf(pha0, W1.x, accE);
            {
                const float s2 = pha1 * W2.x;
                const float s3 = pha2 * W3.x * A0.w;
                ax = fmaf(eqa0, s2, fmaf(s3, A0.x, ax));
                ay = fmaf(eqa1, s2, fmaf(s3, A0.y, ay));
                az = fmaf(eqa2, s2, fmaf(s3, A0.z, az));
            }
            // ---- scalar epilogue, slot b (ph pre-masked) ----
            accE = fmaf(phb0, W1.y, accE);
            {
                const float s2 = phb1 * W2.y;
                const float s3 = phb2 * W3.y * A1.w;
                ax = fmaf(eqb0, s2, fmaf(s3, A1.x, ax));
                ay = fmaf(eqb1, s2, fmaf(s3, A1.y, ay));
                az = fmaf(eqb2, s2, fmaf(s3, A1.z, az));
            }

            // rotate pipeline
            A0 = A2; B0 = B2; A1 = A3; B1 = B3;
        }
    }

    out_emb[(size_t)i * F_DIM + f] = emb_table[z[i] * F_DIM + f] + accE;

    const float* ei = eq     + ((size_t)i * F_DIM + f) * 3;
    float*       od = out_eq + ((size_t)i * F_DIM + f) * 3;
    od[0] = ei[0] + ax;
    od[1] = ei[1] + ay;
    od[2] = ei[2] + az;
}

// ---------------------------------------------------------------------------
extern "C" void kernel_launch(void* const* d_in, const int* in_sizes, int n_in,
                              void* d_out, int out_size, void* d_ws, size_t ws_size,
                              hipStream_t stream) {
    const float* pos       = (const float*)d_in[0];
    const float* eq        = (const float*)d_in[1];
    const float* emb_table = (const float*)d_in[2];
    const float* w_phi1    = (const float*)d_in[3];
    const float* b_phi1    = (const float*)d_in[4];
    const float* w_phi2    = (const float*)d_in[5];
    const float* b_phi2    = (const float*)d_in[6];
    const float* w_rbf     = (const float*)d_in[7];
    const float* b_rbf     = (const float*)d_in[8];
    const int*   z         = (const int*)d_in[9];
    const int*   esrc      = (const int*)d_in[10];
    const int*   edst      = (const int*)d_in[11];

    float* out_emb = (float*)d_out;                               // [N, F]
    float* out_eq  = (float*)d_out + (size_t)N_NODES * F_DIM;     // [N, F, 3]

    // workspace layout (16B-aligned chunks)
    char* ws = (char*)d_ws;
    float4* rec        = (float4*)ws;  ws += (size_t)N_EDGES * 32;
    float*  phi_table  = (float*)ws;   ws += 100 * 3 * F_DIM * 4;
    int*    counts     = (int*)ws;     ws += N_NODES * 4;
    int*    partial    = (int*)ws;     ws += N_NODES * 4;
    int*    offsets    = (int*)ws;     ws += N_NODES * 4;
    int*    cursor     = (int*)ws;     ws += N_NODES * 4;
    int*    chunk_sums = (int*)ws;     ws += SCAN_B * 4;
    int*    chunk_pref = (int*)ws;     ws += SCAN_B * 4;

    hipMemsetAsync(counts, 0, N_NODES * sizeof(int), stream);
    phi_table_kernel<<<100, 3 * F_DIM, 0, stream>>>(emb_table, w_phi1, b_phi1,
                                                    w_phi2, b_phi2, phi_table);
    count_kernel<<<(N_EDGES + 255) / 256, 256, 0, stream>>>(edst, counts);
    scan_partial_kernel<<<N_CHUNK, SCAN_B, 0, stream>>>(counts, partial, chunk_sums);
    scan_sums_kernel<<<1, SCAN_B, 0, stream>>>(chunk_sums, chunk_pref);
    finalize_offsets_kernel<<<(N_NODES + 255) / 256, 256, 0, stream>>>(
        partial, chunk_pref, offsets, cursor);
    edge_pre_kernel<<<(N_EDGES + 255) / 256, 256, 0, stream>>>(
        pos, z, esrc, edst, cursor, rec);
    gather_kernel<<<(N_NODES + 1) / 2, 256, 0, stream>>>(
        eq, emb_table, phi_table, w_rbf, b_rbf, z, rec,
        offsets, counts, out_emb, out_eq);
}

// Round 5
// 537.893 us; speedup vs baseline: 1.0886x; 1.0886x over previous
//
#include <hip/hip_runtime.h>
#include <math.h>

#define N_NODES 50000
#define N_EDGES 400000
#define F_DIM   128
#define N_RBF   20
#define SCAN_B  256
#define N_CHUNK ((N_NODES + SCAN_B - 1) / SCAN_B)   // 196

typedef float f2 __attribute__((ext_vector_type(2)));

// ---------------------------------------------------------------------------
// phi_table[t] = silu(emb_table[t] @ w_phi1 + b_phi1) @ w_phi2 + b_phi2
// ---------------------------------------------------------------------------
__global__ void phi_table_kernel(const float* __restrict__ emb_table,
                                 const float* __restrict__ w_phi1,
                                 const float* __restrict__ b_phi1,
                                 const float* __restrict__ w_phi2,
                                 const float* __restrict__ b_phi2,
                                 float* __restrict__ phi_table) {
    __shared__ float emb_s[F_DIM];
    __shared__ float h_s[F_DIM];
    const int t = blockIdx.x;
    const int o = threadIdx.x;
    if (o < F_DIM) emb_s[o] = emb_table[t * F_DIM + o];
    __syncthreads();
    if (o < F_DIM) {
        float acc = b_phi1[o];
#pragma unroll 8
        for (int k = 0; k < F_DIM; ++k)
            acc = fmaf(emb_s[k], w_phi1[k * F_DIM + o], acc);
        h_s[o] = acc / (1.0f + expf(-acc));   // silu
    }
    __syncthreads();
    float a2 = b_phi2[o];
#pragma unroll 8
    for (int k = 0; k < F_DIM; ++k)
        a2 = fmaf(h_s[k], w_phi2[k * (3 * F_DIM) + o], a2);
    phi_table[t * (3 * F_DIM) + o] = a2;
}

__global__ void count_kernel(const int* __restrict__ edst, int* __restrict__ counts) {
    const int e = blockIdx.x * blockDim.x + threadIdx.x;
    if (e < N_EDGES) atomicAdd(&counts[edst[e]], 1);
}

__global__ void scan_partial_kernel(const int* __restrict__ counts,
                                    int* __restrict__ partial,
                                    int* __restrict__ chunk_sums) {
    __shared__ int s[SCAN_B];
    const int tid = threadIdx.x;
    const int gid = blockIdx.x * SCAN_B + tid;
    const int v = (gid < N_NODES) ? counts[gid] : 0;
    s[tid] = v;
    __syncthreads();
    for (int d = 1; d < SCAN_B; d <<= 1) {
        const int t = (tid >= d) ? s[tid - d] : 0;
        __syncthreads();
        s[tid] += t;
        __syncthreads();
    }
    if (gid < N_NODES) partial[gid] = s[tid] - v;
    if (tid == SCAN_B - 1) chunk_sums[blockIdx.x] = s[tid];
}

__global__ void scan_sums_kernel(int* __restrict__ chunk_sums,
                                 int* __restrict__ chunk_pref) {
    __shared__ int s[SCAN_B];
    const int tid = threadIdx.x;
    const int v = (tid < N_CHUNK) ? chunk_sums[tid] : 0;
    s[tid] = v;
    __syncthreads();
    for (int d = 1; d < SCAN_B; d <<= 1) {
        const int t = (tid >= d) ? s[tid - d] : 0;
        __syncthreads();
        s[tid] += t;
        __syncthreads();
    }
    if (tid < N_CHUNK) chunk_pref[tid] = s[tid] - v;
}

__global__ void finalize_offsets_kernel(const int* __restrict__ partial,
                                        const int* __restrict__ chunk_pref,
                                        int* __restrict__ offsets,
                                        int* __restrict__ cursor) {
    const int i = blockIdx.x * blockDim.x + threadIdx.x;
    if (i >= N_NODES) return;
    const int o = partial[i] + chunk_pref[i >> 8];
    offsets[i] = o;
    cursor[i]  = o;
}

// ---------------------------------------------------------------------------
// Edge-parallel precompute + CSR fill. Per edge, one 32B record at slot p:
//   rec[2p]   = (px, py, pz, d)
//   rec[2p+1] = (j, t, sin(a)/d, 2*cos(a))   [a = pi*d/5]
// ---------------------------------------------------------------------------
__global__ void edge_pre_kernel(const float* __restrict__ pos,
                                const int* __restrict__ z,
                                const int* __restrict__ esrc,
                                const int* __restrict__ edst,
                                int* __restrict__ cursor,
                                float4* __restrict__ rec) {
    const int e = blockIdx.x * blockDim.x + threadIdx.x;
    if (e >= N_EDGES) return;
    const int j = esrc[e];
    const int i = edst[e];
    const int p = atomicAdd(&cursor[i], 1);

    const float px = pos[3 * i + 0] - pos[3 * j + 0];
    const float py = pos[3 * i + 1] - pos[3 * j + 1];
    const float pz = pos[3 * i + 2] - pos[3 * j + 2];
    const float d = sqrtf(px * px + py * py + pz * pz);
    const float inv_d = 1.0f / d;

    float sa, ca;
    sincosf(0.6283185307179586f * d, &sa, &ca);   // pi*d/5

    rec[2 * p] = make_float4(px, py, pz, d);
    float4 b;
    b.x = __int_as_float(j);
    b.y = __int_as_float(z[j]);
    b.z = sa * inv_d;
    b.w = 2.0f * ca;
    rec[2 * p + 1] = b;
}

// ---------------------------------------------------------------------------
// Gather: 128-thread group per node (2/block). Thread f owns outputs
// f, 128+f, 256+f.
//
// R4 post-mortem: the weight ACCESS path (60 global loads + ~40 addr VALU
// per pair) dominates the hot block, and same-iteration eq/phi consumption
// made the kernel latency-bound (VALUBusy 29%). R5:
//  * w_rbf staged in LDS TRANSPOSED to wT[c][f][n]: lane f's 20 weights per
//    channel are 80 contiguous bytes -> 5 ds_read_b128 per channel, base
//    f*80, pure immediate offsets. Zero addr VALU, zero VMEM in the W-block.
//    (b128 quarter-wave stride-80B -> 2-way bank aliasing = free.)
//  * R1's proven pipeline distances restored at pair granularity: rec
//    prefetched TWO pairs ahead; eq/phi gathers issued for pair p+1 from
//    records loaded last iteration, consumed a full iteration later.
//  * Hot FMA block stays packed (v_pk_fma_f32, one edge per half).
// ---------------------------------------------------------------------------
__global__ void __launch_bounds__(256, 2)
gather_kernel(const float* __restrict__ eq,
              const float* __restrict__ emb_table,
              const float* __restrict__ phi_table,
              const float* __restrict__ w_rbf,
              const float* __restrict__ b_rbf,
              const int* __restrict__ z,
              const float4* __restrict__ rec,
              const int* __restrict__ offsets,
              const int* __restrict__ counts,
              float* __restrict__ out_emb,
              float* __restrict__ out_eq) {
    __shared__ float wlds[3 * F_DIM * N_RBF];   // wT[c][f][n], 30720 B
    const int tid = threadIdx.x;

    // one-time stage: coalesced global read, scattered LDS write
    for (int idx = tid; idx < 3 * F_DIM * N_RBF; idx += 256) {
        const int n = idx / (3 * F_DIM);
        const int m = idx - n * (3 * F_DIM);       // 0..383
        const int c = m >> 7;                       // channel
        const int ff = m & 127;
        wlds[c * (F_DIM * N_RBF) + ff * N_RBF + n] = w_rbf[idx];
    }
    __syncthreads();

    const int grp = tid >> 7;
    const int f   = tid & 127;
    const int i   = blockIdx.x * 2 + grp;
    if (i >= N_NODES) return;

    const int start = offsets[i];
    const int cnt   = counts[i];

    const float br1 = b_rbf[f];
    const float br2 = b_rbf[F_DIM + f];
    const float br3 = b_rbf[2 * F_DIM + f];
    const float* wl = &wlds[f * N_RBF];   // +0 / +2560 / +5120 floats per channel

    float accE = 0.f, ax = 0.f, ay = 0.f, az = 0.f;

    if (cnt > 0) {
        const int last = cnt - 1;

        // ---- prologue: recs for pair 0 and pair 1 ----
        float4 A0 = rec[2 * start];
        float4 B0 = rec[2 * start + 1];
        int p = start + min(1, last);
        float4 A1 = rec[2 * p], B1 = rec[2 * p + 1];
        p = start + min(2, last);
        float4 A2 = rec[2 * p], B2 = rec[2 * p + 1];
        p = start + min(3, last);
        float4 A3 = rec[2 * p], B3 = rec[2 * p + 1];

        // eq/phi for pair 0 (slot b clamped; masked at consumption)
        int ja = __float_as_int(B0.x), ta = __float_as_int(B0.y);
        int jb = __float_as_int(B1.x), tb = __float_as_int(B1.y);
        const float* eja = eq + ((size_t)ja * F_DIM + f) * 3;
        const float* ejb = eq + ((size_t)jb * F_DIM + f) * 3;
        float eqa0 = eja[0], eqa1 = eja[1], eqa2 = eja[2];
        float eqb0 = ejb[0], eqb1 = ejb[1], eqb2 = ejb[2];
        const float* pta = phi_table + ta * (3 * F_DIM) + f;
        const float* ptb = phi_table + tb * (3 * F_DIM) + f;
        float pha0 = pta[0], pha1 = pta[F_DIM], pha2 = pta[2 * F_DIM];
        float phb0 = ptb[0], phb1 = ptb[F_DIM], phb2 = ptb[2 * F_DIM];

        for (int base = 0; base < cnt; base += 2) {
            // (a) prefetch recs for pair p+2 (edges base+4, base+5)
            const int q0 = start + min(base + 4, last);
            const int q1 = start + min(base + 5, last);
            const float4 A4 = rec[2 * q0], B4 = rec[2 * q0 + 1];
            const float4 A5 = rec[2 * q1], B5 = rec[2 * q1 + 1];

            // (b) issue eq/phi gathers for pair p+1 (from B2/B3, resident)
            const int jc = __float_as_int(B2.x), tpc = __float_as_int(B2.y);
            const int jd = __float_as_int(B3.x), tpd = __float_as_int(B3.y);
            const float* ejc = eq + ((size_t)jc * F_DIM + f) * 3;
            const float* ejd = eq + ((size_t)jd * F_DIM + f) * 3;
            const float neqa0 = ejc[0], neqa1 = ejc[1], neqa2 = ejc[2];
            const float neqb0 = ejd[0], neqb1 = ejd[1], neqb2 = ejd[2];
            const float* ptc = phi_table + tpc * (3 * F_DIM) + f;
            const float* ptd = phi_table + tpd * (3 * F_DIM) + f;
            const float npha0 = ptc[0], npha1 = ptc[F_DIM], npha2 = ptc[2 * F_DIM];
            const float nphb0 = ptd[0], nphb1 = ptd[F_DIM], nphb2 = ptd[2 * F_DIM];

            // (c) packed W block for pair p: weights via ds_read_b128,
            //     immediate offsets, zero addr VALU
            f2 W1 = {br1, br1};
            f2 W2 = {br2, br2};
            f2 W3 = {br3, br3};
            f2 tcv  = {B0.z, B1.z};
            f2 twoc = {B0.w, B1.w};
            f2 tm1  = {0.0f, 0.0f};
#pragma unroll
            for (int g = 0; g < 5; ++g) {
                const float4 wa = *(const float4*)&wl[g * 4];
                const float4 wb = *(const float4*)&wl[F_DIM * N_RBF + g * 4];
                const float4 wc = *(const float4*)&wl[2 * F_DIM * N_RBF + g * 4];
#pragma unroll
                for (int k = 0; k < 4; ++k) {
                    const float w1 = (k == 0) ? wa.x : (k == 1) ? wa.y : (k == 2) ? wa.z : wa.w;
                    const float w2 = (k == 0) ? wb.x : (k == 1) ? wb.y : (k == 2) ? wb.z : wb.w;
                    const float w3 = (k == 0) ? wc.x : (k == 1) ? wc.y : (k == 2) ? wc.z : wc.w;
                    const f2 w1v = {w1, w1};
                    const f2 w2v = {w2, w2};
                    const f2 w3v = {w3, w3};
                    W1 = __builtin_elementwise_fma(tcv, w1v, W1);
                    W2 = __builtin_elementwise_fma(tcv, w2v, W2);
                    W3 = __builtin_elementwise_fma(tcv, w3v, W3);
                    const f2 tn = __builtin_elementwise_fma(twoc, tcv, -tm1);
                    tm1 = tcv; tcv = tn;
                }
            }

            // (d) scalar epilogue; slot b masked at consumption
            const float mb = (base + 1 < cnt) ? 1.0f : 0.0f;
            accE = fmaf(pha0, W1.x, accE);
            {
                const float s2 = pha1 * W2.x;
                const float s3 = pha2 * W3.x * A0.w;
                ax = fmaf(eqa0, s2, fmaf(s3, A0.x, ax));
                ay = fmaf(eqa1, s2, fmaf(s3, A0.y, ay));
                az = fmaf(eqa2, s2, fmaf(s3, A0.z, az));
            }
            accE = fmaf(mb * phb0, W1.y, accE);
            {
                const float s2 = (mb * phb1) * W2.y;
                const float s3 = (mb * phb2) * W3.y * A1.w;
                ax = fmaf(eqb0, s2, fmaf(s3, A1.x, ax));
                ay = fmaf(eqb1, s2, fmaf(s3, A1.y, ay));
                az = fmaf(eqb2, s2, fmaf(s3, A1.z, az));
            }

            // (e) rotate pipeline
            A0 = A2; B0 = B2; A1 = A3; B1 = B3;
            A2 = A4; B2 = B4; A3 = A5; B3 = B5;
            eqa0 = neqa0; eqa1 = neqa1; eqa2 = neqa2;
            eqb0 = neqb0; eqb1 = neqb1; eqb2 = neqb2;
            pha0 = npha0; pha1 = npha1; pha2 = npha2;
            phb0 = nphb0; phb1 = nphb1; phb2 = nphb2;
        }
    }

    out_emb[(size_t)i * F_DIM + f] = emb_table[z[i] * F_DIM + f] + accE;

    const float* ei = eq     + ((size_t)i * F_DIM + f) * 3;
    float*       od = out_eq + ((size_t)i * F_DIM + f) * 3;
    od[0] = ei[0] + ax;
    od[1] = ei[1] + ay;
    od[2] = ei[2] + az;
}

// ---------------------------------------------------------------------------
extern "C" void kernel_launch(void* const* d_in, const int* in_sizes, int n_in,
                              void* d_out, int out_size, void* d_ws, size_t ws_size,
                              hipStream_t stream) {
    const float* pos       = (const float*)d_in[0];
    const float* eq        = (const float*)d_in[1];
    const float* emb_table = (const float*)d_in[2];
    const float* w_phi1    = (const float*)d_in[3];
    const float* b_phi1    = (const float*)d_in[4];
    const float* w_phi2    = (const float*)d_in[5];
    const float* b_phi2    = (const float*)d_in[6];
    const float* w_rbf     = (const float*)d_in[7];
    const float* b_rbf     = (const float*)d_in[8];
    const int*   z         = (const int*)d_in[9];
    const int*   esrc      = (const int*)d_in[10];
    const int*   edst      = (const int*)d_in[11];

    float* out_emb = (float*)d_out;                               // [N, F]
    float* out_eq  = (float*)d_out + (size_t)N_NODES * F_DIM;     // [N, F, 3]

    // workspace layout (16B-aligned chunks)
    char* ws = (char*)d_ws;
    float4* rec        = (float4*)ws;  ws += (size_t)N_EDGES * 32;
    float*  phi_table  = (float*)ws;   ws += 100 * 3 * F_DIM * 4;
    int*    counts     = (int*)ws;     ws += N_NODES * 4;
    int*    partial    = (int*)ws;     ws += N_NODES * 4;
    int*    offsets    = (int*)ws;     ws += N_NODES * 4;
    int*    cursor     = (int*)ws;     ws += N_NODES * 4;
    int*    chunk_sums = (int*)ws;     ws += SCAN_B * 4;
    int*    chunk_pref = (int*)ws;     ws += SCAN_B * 4;

    hipMemsetAsync(counts, 0, N_NODES * sizeof(int), stream);
    phi_table_kernel<<<100, 3 * F_DIM, 0, stream>>>(emb_table, w_phi1, b_phi1,
                                                    w_phi2, b_phi2, phi_table);
    count_kernel<<<(N_EDGES + 255) / 256, 256, 0, stream>>>(edst, counts);
    scan_partial_kernel<<<N_CHUNK, SCAN_B, 0, stream>>>(counts, partial, chunk_sums);
    scan_sums_kernel<<<1, SCAN_B, 0, stream>>>(chunk_sums, chunk_pref);
    finalize_offsets_kernel<<<(N_NODES + 255) / 256, 256, 0, stream>>>(
        partial, chunk_pref, offsets, cursor);
    edge_pre_kernel<<<(N_EDGES + 255) / 256, 256, 0, stream>>>(
        pos, z, esrc, edst, cursor, rec);
    gather_kernel<<<(N_NODES + 1) / 2, 256, 0, stream>>>(
        eq, emb_table, phi_table, w_rbf, b_rbf, z, rec,
        offsets, counts, out_emb, out_eq);
}